// Round 16
// baseline (19466.422 us; speedup 1.0000x reference)
//
#include <hip/hip_runtime.h>

// Net_46076409152296: spiking net fwd (RLeaky+Leaky). B=1024,T=32,D=2312,H=512,O=10.
// v16: (a) K1 unchanged math + __launch_bounds__(256,2) occupancy probe.
//      (b) K2 sparse-spike rec: per-step index compaction (ballot/popcount),
//          gathers from f64 WrT (K0 transpose, ws base) — skipping zero terms
//          is bit-identical in f64; 4-accumulator order change ~1e-16 (safe).
// All dots f64; fp32 state updates in reference order (validated v10-v15).

constexpr int Bq = 1024, Tq = 32, Dq = 2312, Hq = 512, Oq = 10;

// ---------------- K0: WrT[k][j] = (double)Wr[j][k]  (coalesced transpose)
__global__ __launch_bounds__(256) void snn_wrt(
    const float* __restrict__ Wr, double* __restrict__ WrT) {
  __shared__ float t[32][33];
  const int bx = blockIdx.x;          // k-tile
  const int by = blockIdx.y;          // j-tile
  const int lx = threadIdx.x & 31, ly = threadIdx.x >> 5;  // 32 x 8
#pragma unroll
  for (int i = 0; i < 4; ++i)
    t[ly + 8 * i][lx] = Wr[(size_t)(by * 32 + ly + 8 * i) * Hq + bx * 32 + lx];
  __syncthreads();
#pragma unroll
  for (int i = 0; i < 4; ++i)
    WrT[(size_t)(bx * 32 + ly + 8 * i) * Hq + by * 32 + lx] =
        (double)t[lx][ly + 8 * i];
}

// ---------------- K1: C[m][n] = f64dot(x[m,:], W1[n,:]) + b1[n]  (v15 + (256,2))
__global__ __launch_bounds__(256, 2) void snn_fc1_gemm(
    const float* __restrict__ x, const float* __restrict__ W1,
    const float* __restrict__ b1, float* __restrict__ cur1) {
  __shared__ double Xs[2][8][160];   // chunk c at [kk][c*10..c*10+7]
  __shared__ double Ws[2][8][160];

  const int tid = threadIdx.x;
  const int tx = tid & 15;
  const int ty = tid >> 4;
  const size_t m0 = (size_t)blockIdx.y * 128;
  const int n0 = blockIdx.x * 128;
  const int srow = tid >> 1;
  const int sko = (tid & 1) * 4;
  const int schunk = (srow >> 3) * 10 + (srow & 7);
  const float* __restrict__ ax = x + (m0 + srow) * Dq + sko;
  const float* __restrict__ bx = W1 + (size_t)(n0 + srow) * Dq + sko;

  double acc[8][8];
#pragma unroll
  for (int i = 0; i < 8; ++i)
#pragma unroll
    for (int j = 0; j < 8; ++j) acc[i][j] = 0.0;

  float4 av = *(const float4*)(ax);
  float4 bv = *(const float4*)(bx);
  Xs[0][sko + 0][schunk] = (double)av.x;
  Xs[0][sko + 1][schunk] = (double)av.y;
  Xs[0][sko + 2][schunk] = (double)av.z;
  Xs[0][sko + 3][schunk] = (double)av.w;
  Ws[0][sko + 0][schunk] = (double)bv.x;
  Ws[0][sko + 1][schunk] = (double)bv.y;
  Ws[0][sko + 2][schunk] = (double)bv.z;
  Ws[0][sko + 3][schunk] = (double)bv.w;
  __syncthreads();

  for (int s = 0; s < 289; ++s) {        // D = 289 * 8
    const int buf = s & 1;
    if (s + 1 < 289) {
      av = *(const float4*)(ax + (s + 1) * 8);
      bv = *(const float4*)(bx + (s + 1) * 8);
    }
#pragma unroll
    for (int kk = 0; kk < 8; ++kk) {
      double a[8], b[8];
      *(double2*)&a[0] = *(const double2*)&Xs[buf][kk][ty * 10 + 0];
      *(double2*)&a[2] = *(const double2*)&Xs[buf][kk][ty * 10 + 2];
      *(double2*)&a[4] = *(const double2*)&Xs[buf][kk][ty * 10 + 4];
      *(double2*)&a[6] = *(const double2*)&Xs[buf][kk][ty * 10 + 6];
      *(double2*)&b[0] = *(const double2*)&Ws[buf][kk][tx * 10 + 0];
      *(double2*)&b[2] = *(const double2*)&Ws[buf][kk][tx * 10 + 2];
      *(double2*)&b[4] = *(const double2*)&Ws[buf][kk][tx * 10 + 4];
      *(double2*)&b[6] = *(const double2*)&Ws[buf][kk][tx * 10 + 6];
#pragma unroll
      for (int i = 0; i < 8; ++i)
#pragma unroll
        for (int j = 0; j < 8; ++j) acc[i][j] = fma(a[i], b[j], acc[i][j]);
    }
    if (s + 1 < 289) {
      const int nb = buf ^ 1;
      Xs[nb][sko + 0][schunk] = (double)av.x;
      Xs[nb][sko + 1][schunk] = (double)av.y;
      Xs[nb][sko + 2][schunk] = (double)av.z;
      Xs[nb][sko + 3][schunk] = (double)av.w;
      Ws[nb][sko + 0][schunk] = (double)bv.x;
      Ws[nb][sko + 1][schunk] = (double)bv.y;
      Ws[nb][sko + 2][schunk] = (double)bv.z;
      Ws[nb][sko + 3][schunk] = (double)bv.w;
      __syncthreads();
    }
  }

  float bl[8];
  *(float4*)&bl[0] = *(const float4*)(b1 + n0 + tx * 8);
  *(float4*)&bl[4] = *(const float4*)(b1 + n0 + tx * 8 + 4);
#pragma unroll
  for (int i = 0; i < 8; ++i) {
    float* crow = cur1 + (m0 + ty * 8 + i) * Hq + n0 + tx * 8;
    float4 v0, v1;
    v0.x = __fadd_rn((float)acc[i][0], bl[0]);
    v0.y = __fadd_rn((float)acc[i][1], bl[1]);
    v0.z = __fadd_rn((float)acc[i][2], bl[2]);
    v0.w = __fadd_rn((float)acc[i][3], bl[3]);
    v1.x = __fadd_rn((float)acc[i][4], bl[4]);
    v1.y = __fadd_rn((float)acc[i][5], bl[5]);
    v1.z = __fadd_rn((float)acc[i][6], bl[6]);
    v1.w = __fadd_rn((float)acc[i][7], bl[7]);
    *(float4*)(crow) = v0;
    *(float4*)(crow + 4) = v1;
  }
}

// ---------------- K2 helpers: pipelined sparse gather
__device__ __forceinline__ void gather8(const unsigned short* __restrict__ row,
                                        int base, int j,
                                        const double* __restrict__ WrT,
                                        double* g) {
  const uint4 pk = *(const uint4*)&row[base];
  const int k0 = pk.x & 0xffff, k1 = pk.x >> 16;
  const int k2 = pk.y & 0xffff, k3 = pk.y >> 16;
  const int k4 = pk.z & 0xffff, k5 = pk.z >> 16;
  const int k6 = pk.w & 0xffff, k7 = pk.w >> 16;
  g[0] = WrT[(size_t)k0 * Hq + j];
  g[1] = WrT[(size_t)k1 * Hq + j];
  g[2] = WrT[(size_t)k2 * Hq + j];
  g[3] = WrT[(size_t)k3 * Hq + j];
  g[4] = WrT[(size_t)k4 * Hq + j];
  g[5] = WrT[(size_t)k5 * Hq + j];
  g[6] = WrT[(size_t)k6 * Hq + j];
  g[7] = WrT[(size_t)k7 * Hq + j];
}
__device__ __forceinline__ void acc8(const double* g, int rem, double& rA,
                                     double& rB, double& rC, double& rD) {
  if (rem >= 8) {
    rA += g[0]; rB += g[1]; rC += g[2]; rD += g[3];
    rA += g[4]; rB += g[5]; rC += g[6]; rD += g[7];
  } else {
    if (rem > 0) rA += g[0];
    if (rem > 1) rB += g[1];
    if (rem > 2) rC += g[2];
    if (rem > 3) rD += g[3];
    if (rem > 4) rA += g[4];
    if (rem > 5) rB += g[5];
    if (rem > 6) rC += g[6];
  }
}

// ---------------- K2: sparse-spike recurrent scan
__global__ __launch_bounds__(512) void snn_scan(
    const float* __restrict__ cur1, const double* __restrict__ WrT,
    const float* __restrict__ br, const float* __restrict__ W2,
    const float* __restrict__ b2, float* __restrict__ out, int b_off) {
  __shared__ float spkF[4][512];                // 8 KB (fc2)
  __shared__ unsigned short idxL[4][512];       // 4 KB (active k lists)
  __shared__ unsigned long long masksL[4][8];   // 256 B
  __shared__ int cnts[4];

  const int j = threadIdx.x;
  const int wv = j >> 6;
  const int lane = j & 63;
  const int lb = blockIdx.x * 4;
  const int gb = b_off + lb;

  float m1[4] = {0.f, 0.f, 0.f, 0.f};
  float m2 = 0.f;
#pragma unroll
  for (int r = 0; r < 4; ++r) { spkF[r][j] = 0.f; idxL[r][j] = 0; }
  if (j < 4) cnts[j] = 0;
  __syncthreads();

  const float brr = br[j];

  const int g = j >> 3, l = j & 7;
  const int r2g = g / 10, o2 = g - r2g * 10;
  const bool doB = (j < 320);
  const float b2v = doB ? b2[o2] : 0.f;
  const float* __restrict__ w2p = doB ? (W2 + (size_t)o2 * Hq) : W2;

  for (int t = 0; t < Tq; ++t) {
    float c1[4];
#pragma unroll
    for (int r = 0; r < 4; ++r)
      c1[r] = cur1[((size_t)(lb + r) * Tq + t) * Hq + j];

    // ---- sparse rec: rec[r] = sum over active k of WrT[k][j] ----
    double rec[4];
#pragma unroll
    for (int r = 0; r < 4; ++r) {
      const int cnt = cnts[r];
      double rA = 0.0, rB = 0.0, rC = 0.0, rD = 0.0;
      double g0[8], g1[8];
      if (cnt > 0) gather8(&idxL[r][0], 0, j, WrT, g0);
      for (int i0 = 0; i0 < cnt; i0 += 16) {
        if (i0 + 8 < cnt) gather8(&idxL[r][0], i0 + 8, j, WrT, g1);
        acc8(g0, cnt - i0, rA, rB, rC, rD);
        if (i0 + 16 < cnt) gather8(&idxL[r][0], i0 + 16, j, WrT, g0);
        if (i0 + 8 < cnt) acc8(g1, cnt - (i0 + 8), rA, rB, rC, rD);
      }
      rec[r] = (rA + rB) + (rC + rD);
    }
    __syncthreads();  // rec reads done; idxL/masksL/spkF free to overwrite

    // ---- state update + ballots ----
    unsigned long long bm[4];
    int bits = 0;
#pragma unroll
    for (int r = 0; r < 4; ++r) {
      const float rst = (m1[r] - 1.0f > 0.0f) ? 1.0f : 0.0f;
      const float mn = __fsub_rn(
          __fadd_rn(__fadd_rn(__fmul_rn(0.99f, m1[r]), c1[r]),
                    __fadd_rn((float)rec[r], brr)),
          rst);
      m1[r] = mn;
      const bool bit = (mn - 1.0f > 0.0f);
      spkF[r][j] = bit ? 1.0f : 0.0f;
      if (bit) bits |= (1 << r);
      bm[r] = __ballot(bit);
      if (lane == 0) masksL[r][wv] = bm[r];
    }
    __syncthreads();  // masksL + spkF visible

    // ---- compaction: positions + counts ----
#pragma unroll
    for (int r = 0; r < 4; ++r) {
      int base = 0;
#pragma unroll
      for (int w = 0; w < 8; ++w)
        if (w < wv) base += __popcll(masksL[r][w]);
      if (bits & (1 << r)) {
        const int pos = base + __popcll(bm[r] & ((1ull << lane) - 1ull));
        idxL[r][pos] = (unsigned short)j;
      }
    }
    if (j < 4) {
      int c = 0;
#pragma unroll
      for (int w = 0; w < 8; ++w) c += __popcll(masksL[j][w]);
      cnts[j] = c;
    }
    // ---- fc2 + mem2 + outputs (dense, 8 lanes per dot) ----
    if (doB) {
      double p = 0.0;
#pragma unroll
      for (int s8 = 0; s8 < 64; ++s8) {
        const int k = l + (s8 << 3);
        p = fma((double)spkF[r2g][k], (double)w2p[k], p);
      }
      p += __shfl_down(p, 4, 8);
      p += __shfl_down(p, 2, 8);
      p += __shfl_down(p, 1, 8);
      if (l == 0) {
        const float cur2 = __fadd_rn((float)p, b2v);
        const float rst2 = (m2 - 1.0f > 0.0f) ? 1.0f : 0.0f;
        const float mn2 =
            __fsub_rn(__fadd_rn(__fmul_rn(0.99f, m2), cur2), rst2);
        m2 = mn2;
        const size_t oidx = ((size_t)t * Bq + (gb + r2g)) * Oq + o2;
        out[oidx] = (mn2 - 1.0f > 0.0f) ? 1.0f : 0.0f;  // spk2
        out[(size_t)Tq * Bq * Oq + oidx] = mn2;         // mem2
      }
    }
    __syncthreads();  // idxL/cnts ready for next step's rec
  }
}

extern "C" void kernel_launch(void* const* d_in, const int* in_sizes, int n_in,
                              void* d_out, int out_size, void* d_ws, size_t ws_size,
                              hipStream_t stream) {
  const float* x  = (const float*)d_in[0];
  const float* W1 = (const float*)d_in[1];
  const float* b1 = (const float*)d_in[2];
  const float* Wr = (const float*)d_in[3];
  const float* br = (const float*)d_in[4];
  const float* W2 = (const float*)d_in[5];
  const float* b2 = (const float*)d_in[6];
  float* out = (float*)d_out;  // FP32
  (void)in_sizes; (void)n_in; (void)out_size;

  double* WrT = (double*)d_ws;                       // 2 MB
  float* cur1 = (float*)d_ws + 2 * Hq * Hq;          // after WrT (in floats)
  const size_t avail = ws_size - (size_t)Hq * Hq * sizeof(double);

  snn_wrt<<<dim3(16, 16), 256, 0, stream>>>(Wr, WrT);

  int nb = Bq;
  while (nb > 4 && (size_t)nb * Tq * Hq * sizeof(float) > avail) nb >>= 1;

  for (int b_off = 0; b_off < Bq; b_off += nb) {
    snn_fc1_gemm<<<dim3(Hq / 128, nb * Tq / 128), 256, 0, stream>>>(
        x + (size_t)b_off * Tq * Dq, W1, b1, cur1);
    snn_scan<<<nb / 4, 512, 0, stream>>>(cur1, WrT, br, W2, b2, out, b_off);
  }
}

// Round 17
// 3163.507 us; speedup vs baseline: 6.1534x; 6.1534x over previous
//
#include <hip/hip_runtime.h>

// Net_46076409152296: spiking net fwd (RLeaky+Leaky). B=1024,T=32,D=2312,H=512,O=10.
// v17: K1 reverted to v15-exact (plain launch_bounds(256); v16's (256,2) forced
// VGPR 212->128 and spilled the f64 acc to scratch: 90GB traffic, 7x slowdown).
// K0 + sparse K2 kept from v16 (absmax-identical) to measure sparse-rec payoff.

constexpr int Bq = 1024, Tq = 32, Dq = 2312, Hq = 512, Oq = 10;

// ---------------- K0: WrT[k][j] = (double)Wr[j][k]  (coalesced transpose)
__global__ __launch_bounds__(256) void snn_wrt(
    const float* __restrict__ Wr, double* __restrict__ WrT) {
  __shared__ float t[32][33];
  const int bx = blockIdx.x;          // k-tile
  const int by = blockIdx.y;          // j-tile
  const int lx = threadIdx.x & 31, ly = threadIdx.x >> 5;  // 32 x 8
#pragma unroll
  for (int i = 0; i < 4; ++i)
    t[ly + 8 * i][lx] = Wr[(size_t)(by * 32 + ly + 8 * i) * Hq + bx * 32 + lx];
  __syncthreads();
#pragma unroll
  for (int i = 0; i < 4; ++i)
    WrT[(size_t)(bx * 32 + ly + 8 * i) * Hq + by * 32 + lx] =
        (double)t[lx][ly + 8 * i];
}

// ---------------- K1: C[m][n] = f64dot(x[m,:], W1[n,:]) + b1[n]  (v15 verbatim)
__global__ __launch_bounds__(256) void snn_fc1_gemm(
    const float* __restrict__ x, const float* __restrict__ W1,
    const float* __restrict__ b1, float* __restrict__ cur1) {
  __shared__ double Xs[2][8][160];   // chunk c at [kk][c*10..c*10+7]
  __shared__ double Ws[2][8][160];

  const int tid = threadIdx.x;
  const int tx = tid & 15;
  const int ty = tid >> 4;
  const size_t m0 = (size_t)blockIdx.y * 128;
  const int n0 = blockIdx.x * 128;
  const int srow = tid >> 1;
  const int sko = (tid & 1) * 4;
  const int schunk = (srow >> 3) * 10 + (srow & 7);
  const float* __restrict__ ax = x + (m0 + srow) * Dq + sko;
  const float* __restrict__ bx = W1 + (size_t)(n0 + srow) * Dq + sko;

  double acc[8][8];
#pragma unroll
  for (int i = 0; i < 8; ++i)
#pragma unroll
    for (int j = 0; j < 8; ++j) acc[i][j] = 0.0;

  float4 av = *(const float4*)(ax);
  float4 bv = *(const float4*)(bx);
  Xs[0][sko + 0][schunk] = (double)av.x;
  Xs[0][sko + 1][schunk] = (double)av.y;
  Xs[0][sko + 2][schunk] = (double)av.z;
  Xs[0][sko + 3][schunk] = (double)av.w;
  Ws[0][sko + 0][schunk] = (double)bv.x;
  Ws[0][sko + 1][schunk] = (double)bv.y;
  Ws[0][sko + 2][schunk] = (double)bv.z;
  Ws[0][sko + 3][schunk] = (double)bv.w;
  __syncthreads();

  for (int s = 0; s < 289; ++s) {        // D = 289 * 8
    const int buf = s & 1;
    if (s + 1 < 289) {
      av = *(const float4*)(ax + (s + 1) * 8);
      bv = *(const float4*)(bx + (s + 1) * 8);
    }
#pragma unroll
    for (int kk = 0; kk < 8; ++kk) {
      double a[8], b[8];
      *(double2*)&a[0] = *(const double2*)&Xs[buf][kk][ty * 10 + 0];
      *(double2*)&a[2] = *(const double2*)&Xs[buf][kk][ty * 10 + 2];
      *(double2*)&a[4] = *(const double2*)&Xs[buf][kk][ty * 10 + 4];
      *(double2*)&a[6] = *(const double2*)&Xs[buf][kk][ty * 10 + 6];
      *(double2*)&b[0] = *(const double2*)&Ws[buf][kk][tx * 10 + 0];
      *(double2*)&b[2] = *(const double2*)&Ws[buf][kk][tx * 10 + 2];
      *(double2*)&b[4] = *(const double2*)&Ws[buf][kk][tx * 10 + 4];
      *(double2*)&b[6] = *(const double2*)&Ws[buf][kk][tx * 10 + 6];
#pragma unroll
      for (int i = 0; i < 8; ++i)
#pragma unroll
        for (int j = 0; j < 8; ++j) acc[i][j] = fma(a[i], b[j], acc[i][j]);
    }
    if (s + 1 < 289) {
      const int nb = buf ^ 1;
      Xs[nb][sko + 0][schunk] = (double)av.x;
      Xs[nb][sko + 1][schunk] = (double)av.y;
      Xs[nb][sko + 2][schunk] = (double)av.z;
      Xs[nb][sko + 3][schunk] = (double)av.w;
      Ws[nb][sko + 0][schunk] = (double)bv.x;
      Ws[nb][sko + 1][schunk] = (double)bv.y;
      Ws[nb][sko + 2][schunk] = (double)bv.z;
      Ws[nb][sko + 3][schunk] = (double)bv.w;
      __syncthreads();
    }
  }

  float bl[8];
  *(float4*)&bl[0] = *(const float4*)(b1 + n0 + tx * 8);
  *(float4*)&bl[4] = *(const float4*)(b1 + n0 + tx * 8 + 4);
#pragma unroll
  for (int i = 0; i < 8; ++i) {
    float* crow = cur1 + (m0 + ty * 8 + i) * Hq + n0 + tx * 8;
    float4 v0, v1;
    v0.x = __fadd_rn((float)acc[i][0], bl[0]);
    v0.y = __fadd_rn((float)acc[i][1], bl[1]);
    v0.z = __fadd_rn((float)acc[i][2], bl[2]);
    v0.w = __fadd_rn((float)acc[i][3], bl[3]);
    v1.x = __fadd_rn((float)acc[i][4], bl[4]);
    v1.y = __fadd_rn((float)acc[i][5], bl[5]);
    v1.z = __fadd_rn((float)acc[i][6], bl[6]);
    v1.w = __fadd_rn((float)acc[i][7], bl[7]);
    *(float4*)(crow) = v0;
    *(float4*)(crow + 4) = v1;
  }
}

// ---------------- K2 helpers: pipelined sparse gather
__device__ __forceinline__ void gather8(const unsigned short* __restrict__ row,
                                        int base, int j,
                                        const double* __restrict__ WrT,
                                        double* g) {
  const uint4 pk = *(const uint4*)&row[base];
  const int k0 = pk.x & 0xffff, k1 = pk.x >> 16;
  const int k2 = pk.y & 0xffff, k3 = pk.y >> 16;
  const int k4 = pk.z & 0xffff, k5 = pk.z >> 16;
  const int k6 = pk.w & 0xffff, k7 = pk.w >> 16;
  g[0] = WrT[(size_t)k0 * Hq + j];
  g[1] = WrT[(size_t)k1 * Hq + j];
  g[2] = WrT[(size_t)k2 * Hq + j];
  g[3] = WrT[(size_t)k3 * Hq + j];
  g[4] = WrT[(size_t)k4 * Hq + j];
  g[5] = WrT[(size_t)k5 * Hq + j];
  g[6] = WrT[(size_t)k6 * Hq + j];
  g[7] = WrT[(size_t)k7 * Hq + j];
}
__device__ __forceinline__ void acc8(const double* g, int rem, double& rA,
                                     double& rB, double& rC, double& rD) {
  if (rem >= 8) {
    rA += g[0]; rB += g[1]; rC += g[2]; rD += g[3];
    rA += g[4]; rB += g[5]; rC += g[6]; rD += g[7];
  } else {
    if (rem > 0) rA += g[0];
    if (rem > 1) rB += g[1];
    if (rem > 2) rC += g[2];
    if (rem > 3) rD += g[3];
    if (rem > 4) rA += g[4];
    if (rem > 5) rB += g[5];
    if (rem > 6) rC += g[6];
  }
}

// ---------------- K2: sparse-spike recurrent scan (v16 verbatim)
__global__ __launch_bounds__(512) void snn_scan(
    const float* __restrict__ cur1, const double* __restrict__ WrT,
    const float* __restrict__ br, const float* __restrict__ W2,
    const float* __restrict__ b2, float* __restrict__ out, int b_off) {
  __shared__ float spkF[4][512];                // 8 KB (fc2)
  __shared__ unsigned short idxL[4][512];       // 4 KB (active k lists)
  __shared__ unsigned long long masksL[4][8];   // 256 B
  __shared__ int cnts[4];

  const int j = threadIdx.x;
  const int wv = j >> 6;
  const int lane = j & 63;
  const int lb = blockIdx.x * 4;
  const int gb = b_off + lb;

  float m1[4] = {0.f, 0.f, 0.f, 0.f};
  float m2 = 0.f;
#pragma unroll
  for (int r = 0; r < 4; ++r) { spkF[r][j] = 0.f; idxL[r][j] = 0; }
  if (j < 4) cnts[j] = 0;
  __syncthreads();

  const float brr = br[j];

  const int g = j >> 3, l = j & 7;
  const int r2g = g / 10, o2 = g - r2g * 10;
  const bool doB = (j < 320);
  const float b2v = doB ? b2[o2] : 0.f;
  const float* __restrict__ w2p = doB ? (W2 + (size_t)o2 * Hq) : W2;

  for (int t = 0; t < Tq; ++t) {
    float c1[4];
#pragma unroll
    for (int r = 0; r < 4; ++r)
      c1[r] = cur1[((size_t)(lb + r) * Tq + t) * Hq + j];

    // ---- sparse rec: rec[r] = sum over active k of WrT[k][j] ----
    double rec[4];
#pragma unroll
    for (int r = 0; r < 4; ++r) {
      const int cnt = cnts[r];
      double rA = 0.0, rB = 0.0, rC = 0.0, rD = 0.0;
      double g0[8], g1[8];
      if (cnt > 0) gather8(&idxL[r][0], 0, j, WrT, g0);
      for (int i0 = 0; i0 < cnt; i0 += 16) {
        if (i0 + 8 < cnt) gather8(&idxL[r][0], i0 + 8, j, WrT, g1);
        acc8(g0, cnt - i0, rA, rB, rC, rD);
        if (i0 + 16 < cnt) gather8(&idxL[r][0], i0 + 16, j, WrT, g0);
        if (i0 + 8 < cnt) acc8(g1, cnt - (i0 + 8), rA, rB, rC, rD);
      }
      rec[r] = (rA + rB) + (rC + rD);
    }
    __syncthreads();  // rec reads done; idxL/masksL/spkF free to overwrite

    // ---- state update + ballots ----
    unsigned long long bm[4];
    int bits = 0;
#pragma unroll
    for (int r = 0; r < 4; ++r) {
      const float rst = (m1[r] - 1.0f > 0.0f) ? 1.0f : 0.0f;
      const float mn = __fsub_rn(
          __fadd_rn(__fadd_rn(__fmul_rn(0.99f, m1[r]), c1[r]),
                    __fadd_rn((float)rec[r], brr)),
          rst);
      m1[r] = mn;
      const bool bit = (mn - 1.0f > 0.0f);
      spkF[r][j] = bit ? 1.0f : 0.0f;
      if (bit) bits |= (1 << r);
      bm[r] = __ballot(bit);
      if (lane == 0) masksL[r][wv] = bm[r];
    }
    __syncthreads();  // masksL + spkF visible

    // ---- compaction: positions + counts ----
#pragma unroll
    for (int r = 0; r < 4; ++r) {
      int base = 0;
#pragma unroll
      for (int w = 0; w < 8; ++w)
        if (w < wv) base += __popcll(masksL[r][w]);
      if (bits & (1 << r)) {
        const int pos = base + __popcll(bm[r] & ((1ull << lane) - 1ull));
        idxL[r][pos] = (unsigned short)j;
      }
    }
    if (j < 4) {
      int c = 0;
#pragma unroll
      for (int w = 0; w < 8; ++w) c += __popcll(masksL[j][w]);
      cnts[j] = c;
    }
    // ---- fc2 + mem2 + outputs (dense, 8 lanes per dot) ----
    if (doB) {
      double p = 0.0;
#pragma unroll
      for (int s8 = 0; s8 < 64; ++s8) {
        const int k = l + (s8 << 3);
        p = fma((double)spkF[r2g][k], (double)w2p[k], p);
      }
      p += __shfl_down(p, 4, 8);
      p += __shfl_down(p, 2, 8);
      p += __shfl_down(p, 1, 8);
      if (l == 0) {
        const float cur2 = __fadd_rn((float)p, b2v);
        const float rst2 = (m2 - 1.0f > 0.0f) ? 1.0f : 0.0f;
        const float mn2 =
            __fsub_rn(__fadd_rn(__fmul_rn(0.99f, m2), cur2), rst2);
        m2 = mn2;
        const size_t oidx = ((size_t)t * Bq + (gb + r2g)) * Oq + o2;
        out[oidx] = (mn2 - 1.0f > 0.0f) ? 1.0f : 0.0f;  // spk2
        out[(size_t)Tq * Bq * Oq + oidx] = mn2;         // mem2
      }
    }
    __syncthreads();  // idxL/cnts ready for next step's rec
  }
}

extern "C" void kernel_launch(void* const* d_in, const int* in_sizes, int n_in,
                              void* d_out, int out_size, void* d_ws, size_t ws_size,
                              hipStream_t stream) {
  const float* x  = (const float*)d_in[0];
  const float* W1 = (const float*)d_in[1];
  const float* b1 = (const float*)d_in[2];
  const float* Wr = (const float*)d_in[3];
  const float* br = (const float*)d_in[4];
  const float* W2 = (const float*)d_in[5];
  const float* b2 = (const float*)d_in[6];
  float* out = (float*)d_out;  // FP32
  (void)in_sizes; (void)n_in; (void)out_size;

  double* WrT = (double*)d_ws;                       // 2 MB
  float* cur1 = (float*)d_ws + 2 * Hq * Hq;          // after WrT (in floats)
  const size_t avail = ws_size - (size_t)Hq * Hq * sizeof(double);

  snn_wrt<<<dim3(16, 16), 256, 0, stream>>>(Wr, WrT);

  int nb = Bq;
  while (nb > 4 && (size_t)nb * Tq * Hq * sizeof(float) > avail) nb >>= 1;

  for (int b_off = 0; b_off < Bq; b_off += nb) {
    snn_fc1_gemm<<<dim3(Hq / 128, nb * Tq / 128), 256, 0, stream>>>(
        x + (size_t)b_off * Tq * Dq, W1, b1, cur1);
    snn_scan<<<nb / 4, 512, 0, stream>>>(cur1, WrT, br, W2, b2, out, b_off);
  }
}